// Round 1
// baseline (134.830 us; speedup 1.0000x reference)
//
#include <hip/hip_runtime.h>
#include <math.h>

// Problem geometry
#define GRID 65536              // 256*256
#define NFIL 12
#define NTm1 9                  // NT-1 timestep pairs

static constexpr double PI_d = 3.14159265358979323846;

__constant__ int c_xpos[NFIL] = {40,48,56,64,112,120,128,136,184,192,200,208};

// ---------------------------------------------------------------------------
// K[f][i][j] = sum_{jj=0..255} 1/sqrt((x_i - xf_f)^2 + ((j-jj)*DY)^2 + z^2)
// Computed via inclusive prefix sum of g[d] = 1/sqrt(dx2 + (d*DY)^2 + z2):
//   K[j] = Pref[j] + Pref[255-j] - g[0]
// One block per (f,i) pair; 256 threads = one per d (and per output j).
// ---------------------------------------------------------------------------
__global__ void build_K(float* __restrict__ Kmat) {
    const int f = blockIdx.x >> 8;          // 0..11
    const int i = blockIdx.x & 255;         // 0..255
    const int d = threadIdx.x;              // 0..255

    const double dxv = (double)(i - c_xpos[f]) * 20e-9;
    const double r2  = dxv * dxv + 1e-14;   // dx^2 + z^2  (z = 100e-9)
    const double dy  = (double)d * 20e-9;
    const double g   = 1.0 / sqrt(r2 + dy * dy);

    __shared__ double pref[256];
    pref[d] = g;
    __syncthreads();
    // Hillis-Steele inclusive scan over 256 elements
    for (int off = 1; off < 256; off <<= 1) {
        const double add = (d >= off) ? pref[d - off] : 0.0;
        __syncthreads();
        pref[d] += add;
        __syncthreads();
    }
    const double g0 = 1.0 / sqrt(r2);
    Kmat[(blockIdx.x << 8) + d] = (float)(pref[d] + pref[255 - d] - g0);
}

// ---------------------------------------------------------------------------
// dS[k][i][j] = grad_x( mz[k+1] - mz[k] )[i][j]   (numpy.gradient convention,
// WITHOUT any scale factors -- all constants folded into coef in dotK)
// ---------------------------------------------------------------------------
__global__ void build_dS(const float* __restrict__ m, float* __restrict__ dS) {
    const int idx = blockIdx.x * 256 + threadIdx.x;   // < 9*65536 exactly
    const int k   = idx >> 16;
    const int ij  = idx & 65535;
    const int i   = ij >> 8;
    const float* mz0 = m + (size_t)(3 * k + 2) * GRID;  // m[k][2]
    const float* mz1 = m + (size_t)(3 * k + 5) * GRID;  // m[k+1][2]
    float v;
    if (i == 0) {
        v = (mz1[ij + 256] - mz0[ij + 256]) - (mz1[ij] - mz0[ij]);
    } else if (i == 255) {
        v = (mz1[ij] - mz0[ij]) - (mz1[ij - 256] - mz0[ij - 256]);
    } else {
        v = 0.5f * ((mz1[ij + 256] - mz0[ij + 256]) - (mz1[ij - 256] - mz0[ij - 256]));
    }
    dS[idx] = v;
}

// ---------------------------------------------------------------------------
// deltaV[k][f] = coef * sum_{i,j} dS[k][i][j] * K[f][i][j]
// coef = -(2*Msat*DY^2*DZ*1e-7)/DT   (DX cancels; MU0/(4pi) = 1e-7)
// One block of 256 threads per (k,f); double accumulation.
// ---------------------------------------------------------------------------
__global__ void dotK(const float* __restrict__ dS, const float* __restrict__ Kmat,
                     const float* __restrict__ msat_p, float* __restrict__ dV) {
    const int k = blockIdx.x / NFIL;
    const int f = blockIdx.x - NFIL * k;
    const float* a = dS   + (size_t)k * GRID;
    const float* b = Kmat + (size_t)f * GRID;
    double acc = 0.0;
    for (int idx = threadIdx.x; idx < GRID; idx += 256)
        acc = fma((double)a[idx], (double)b[idx], acc);
    // wave64 butterfly, then cross-wave via LDS
    for (int off = 32; off > 0; off >>= 1)
        acc += __shfl_down(acc, off, 64);
    __shared__ double part[4];
    const int lane = threadIdx.x & 63, wid = threadIdx.x >> 6;
    if (lane == 0) part[wid] = acc;
    __syncthreads();
    if (threadIdx.x == 0) {
        const double tot  = part[0] + part[1] + part[2] + part[3];
        const double msat = (double)msat_p[0];
        const double coef = -2.0 * msat * 1e-7 * (20e-9) * (20e-9) * (20e-9) / 5e-12;
        dV[blockIdx.x] = (float)(coef * tot);
    }
}

// ---------------------------------------------------------------------------
// Epilogue: single-frequency DFT fit.
//   re[f] = (2/9) * sum_k cos[k]*dV[k][f];  im likewise with sin
//   ffit[k][f] = cos[k]*re[f] + sin[k]*im[f]
// out[0..107] = deltaV, out[108..215] = ffit
// ---------------------------------------------------------------------------
__global__ void finalize(const float* __restrict__ dV, float* __restrict__ out) {
    __shared__ double cs[NTm1], sn[NTm1], re[NFIL], im[NFIL];
    const int t = threadIdx.x;
    if (t < NTm1) {
        const double tt = (double)(2991 + t) * 5e-12;   // TIMESTEPS-NT+1 = 2991
        const double ph = 2.0 * PI_d * 6.0e9 * tt;
        cs[t] = cos(ph);
        sn[t] = sin(ph);
    }
    __syncthreads();
    if (t < NFIL) {
        double r = 0.0, s = 0.0;
        for (int kk = 0; kk < NTm1; ++kk) {
            const double v = (double)dV[kk * NFIL + t];
            r += cs[kk] * v;
            s += sn[kk] * v;
        }
        re[t] = r * (2.0 / 9.0);
        im[t] = s * (2.0 / 9.0);
    }
    __syncthreads();
    if (t < NTm1 * NFIL) {
        out[t] = dV[t];
        const int kk = t / NFIL, f = t - NFIL * kk;
        out[NTm1 * NFIL + t] = (float)(cs[kk] * re[f] + sn[kk] * im[f]);
    }
}

// ---------------------------------------------------------------------------
extern "C" void kernel_launch(void* const* d_in, const int* in_sizes, int n_in,
                              void* d_out, int out_size, void* d_ws, size_t ws_size,
                              hipStream_t stream) {
    (void)in_sizes; (void)n_in; (void)out_size; (void)ws_size;
    const float* m      = (const float*)d_in[0];   // [10][3][256][256] f32
    const float* msat_p = (const float*)d_in[1];   // scalar f32
    float* out = (float*)d_out;                    // 216 f32
    float* ws  = (float*)d_ws;

    float* Kmat = ws;                               // 12*65536 = 786432 f32
    float* dS   = ws + (size_t)NFIL * GRID;         // 9*65536  = 589824 f32
    float* dV   = dS + (size_t)NTm1 * GRID;         // 108 f32

    build_K <<<NFIL * 256, 256, 0, stream>>>(Kmat);
    build_dS<<<(NTm1 * GRID) / 256, 256, 0, stream>>>(m, dS);
    dotK    <<<NTm1 * NFIL, 256, 0, stream>>>(dS, Kmat, msat_p, dV);
    finalize<<<1, 128, 0, stream>>>(dV, out);
}

// Round 2
// 67.231 us; speedup vs baseline: 2.0055x; 2.0055x over previous
//
#include <hip/hip_runtime.h>
#include <math.h>

#define GRID   65536            // 256*256
#define NFIL   12
#define NTm1   9                // NT-1 timestep pairs
#define UMAX   216              // distinct |i - xpos| values: 0..215
#define GROUPS 64               // row-groups per timestep
#define RPG    4                // rows per group (GROUPS*RPG == 256)

static constexpr double PI_d = 3.14159265358979323846;

__constant__ int c_xpos[NFIL] = {40,48,56,64,112,120,128,136,184,192,200,208};

// ---------------------------------------------------------------------------
// Ktab[u][j] = sum_{jj=0..255} 1/sqrt((u*DX)^2 + ((j-jj)*DY)^2 + z^2)
// via inclusive prefix sum of g[d] = 1/sqrt(u^2 dx^2 + d^2 dy^2 + z^2):
//   Ktab[j] = Pref[j] + Pref[255-j] - g[0]
// One block per u; 256 threads = one per d (and per output j).
// ---------------------------------------------------------------------------
__global__ __launch_bounds__(256) void build_Ktab(float* __restrict__ Kt) {
    const int u = blockIdx.x;               // 0..215
    const int d = threadIdx.x;              // 0..255

    const double dxv = (double)u * 20e-9;
    const double r2  = dxv * dxv + 1e-14;   // (u*DX)^2 + z^2   (z = 100e-9)
    const double dy  = (double)d * 20e-9;
    const double g   = 1.0 / sqrt(r2 + dy * dy);

    __shared__ double pref[256];
    pref[d] = g;
    __syncthreads();
    for (int off = 1; off < 256; off <<= 1) {   // Hillis-Steele inclusive scan
        const double add = (d >= off) ? pref[d - off] : 0.0;
        __syncthreads();
        pref[d] += add;
        __syncthreads();
    }
    const double g0 = 1.0 / sqrt(r2);
    Kt[(u << 8) + d] = (float)(pref[d] + pref[255 - d] - g0);
}

// ---------------------------------------------------------------------------
// Fused gradient + dot:  partial[k][g][f] = sum over rows i in group g, all j:
//     grad_x(mz[k+1]-mz[k])[i][j] * Ktab[|i-xpos[f]|][j]
// One block per (k,g); thread = column j; 12 independent f64 accumulators.
// ---------------------------------------------------------------------------
__global__ __launch_bounds__(256) void fused_dot(const float* __restrict__ m,
                                                 const float* __restrict__ Kt,
                                                 double* __restrict__ partials) {
    const int k = blockIdx.x / GROUPS;      // 0..8
    const int g = blockIdx.x % GROUPS;      // 0..63
    const int j = threadIdx.x;              // 0..255

    const float* mz0 = m + (size_t)(3 * k + 2) * GRID;  // m[k][2]
    const float* mz1 = m + (size_t)(3 * k + 5) * GRID;  // m[k+1][2]

    double acc[NFIL];
#pragma unroll
    for (int f = 0; f < NFIL; ++f) acc[f] = 0.0;

#pragma unroll
    for (int r = 0; r < RPG; ++r) {
        const int i  = g * RPG + r;
        const int im = (i == 0)   ? 0   : i - 1;
        const int ip = (i == 255) ? 255 : i + 1;
        const float sc = (i == 0 || i == 255) ? 1.0f : 0.5f;
        const float dm = sc * ((mz1[ip * 256 + j] - mz0[ip * 256 + j])
                             - (mz1[im * 256 + j] - mz0[im * 256 + j]));
        const double dmd = (double)dm;
#pragma unroll
        for (int f = 0; f < NFIL; ++f) {
            const int u = abs(i - c_xpos[f]);
            acc[f] = fma(dmd, (double)Kt[(u << 8) + j], acc[f]);
        }
    }

    // block reduction: wave64 butterfly per f, then cross-wave via LDS
    __shared__ double lds[4][NFIL];
    const int lane = threadIdx.x & 63, wid = threadIdx.x >> 6;
#pragma unroll
    for (int f = 0; f < NFIL; ++f) {
        double v = acc[f];
        for (int off = 32; off > 0; off >>= 1)
            v += __shfl_down(v, off, 64);
        if (lane == 0) lds[wid][f] = v;
    }
    __syncthreads();
    if (threadIdx.x < NFIL)
        partials[(size_t)blockIdx.x * NFIL + threadIdx.x] =
            lds[0][threadIdx.x] + lds[1][threadIdx.x] +
            lds[2][threadIdx.x] + lds[3][threadIdx.x];
}

// ---------------------------------------------------------------------------
// Reduce partials -> deltaV, then single-frequency DFT fit.
// out[0..107] = deltaV, out[108..215] = ffit
// ---------------------------------------------------------------------------
__global__ __launch_bounds__(128) void finalize(const double* __restrict__ partials,
                                                const float* __restrict__ msat_p,
                                                float* __restrict__ out) {
    __shared__ double cs[NTm1], sn[NTm1], re[NFIL], im[NFIL], dV[NTm1 * NFIL];
    const int t = threadIdx.x;
    if (t < NTm1) {
        const double tt = (double)(2991 + t) * 5e-12;   // TIMESTEPS-NT+1 = 2991
        const double ph = 2.0 * PI_d * 6.0e9 * tt;
        cs[t] = cos(ph);
        sn[t] = sin(ph);
    }
    if (t < NTm1 * NFIL) {
        const int k = t / NFIL, f = t - NFIL * k;
        double s = 0.0;
        for (int g = 0; g < GROUPS; ++g)
            s += partials[(size_t)(k * GROUPS + g) * NFIL + f];
        const double msat = (double)msat_p[0];
        // coef = -(2*Msat*DY*DY*DZ*1e-7)/DT  (DX cancels; MU0/4pi = 1e-7)
        const double coef = -2.0 * msat * 1e-7 * (20e-9) * (20e-9) * (20e-9) / 5e-12;
        dV[t] = coef * s;
    }
    __syncthreads();
    if (t < NFIL) {
        double r = 0.0, s = 0.0;
        for (int kk = 0; kk < NTm1; ++kk) {
            const double v = dV[kk * NFIL + t];
            r += cs[kk] * v;
            s += sn[kk] * v;
        }
        re[t] = r * (2.0 / 9.0);
        im[t] = s * (2.0 / 9.0);
    }
    __syncthreads();
    if (t < NTm1 * NFIL) {
        out[t] = (float)dV[t];
        const int kk = t / NFIL, f = t - NFIL * kk;
        out[NTm1 * NFIL + t] = (float)(cs[kk] * re[f] + sn[kk] * im[f]);
    }
}

// ---------------------------------------------------------------------------
extern "C" void kernel_launch(void* const* d_in, const int* in_sizes, int n_in,
                              void* d_out, int out_size, void* d_ws, size_t ws_size,
                              hipStream_t stream) {
    (void)in_sizes; (void)n_in; (void)out_size; (void)ws_size;
    const float* m      = (const float*)d_in[0];   // [10][3][256][256] f32
    const float* msat_p = (const float*)d_in[1];   // scalar f32
    float* out = (float*)d_out;                    // 216 f32

    float*  Kt       = (float*)d_ws;                         // 216*256 f32 = 221 KB
    double* partials = (double*)((char*)d_ws + ((size_t)UMAX * 256 * sizeof(float) + 255 & ~(size_t)255));
                                                             // 9*64*12 f64 = 55 KB

    build_Ktab<<<UMAX, 256, 0, stream>>>(Kt);
    fused_dot <<<NTm1 * GROUPS, 256, 0, stream>>>(m, Kt, partials);
    finalize  <<<1, 128, 0, stream>>>(partials, msat_p, out);
}